// Round 2
// baseline (720.735 us; speedup 1.0000x reference)
//
#include <hip/hip_runtime.h>
#include <hip/hip_bf16.h>

#define QN 53
#define NTOK 49
#define DIM 192
#define NP 4

typedef __attribute__((ext_vector_type(8))) short short8;
typedef __attribute__((ext_vector_type(4))) float f32x4;

__device__ __forceinline__ unsigned short f2b(float f) {
  union { __hip_bfloat16 h; unsigned short u; } cv;
  cv.h = __float2bfloat16(f);
  return cv.u;
}

// ---------------- prep: bf16 transposed weights (+scale fold) + rpb table ----------------
// rpb layout: [h][qr][key] (6*49*49 floats), window-independent
__global__ void prep_all(const float* __restrict__ q_w, const float* __restrict__ q_b,
                         const float* __restrict__ kv_w, const float* __restrict__ proj_w,
                         const float* __restrict__ bias_table,
                         unsigned short* __restrict__ wq_t, unsigned short* __restrict__ wkv_t,
                         unsigned short* __restrict__ wp_t, float* __restrict__ qb_s,
                         float* __restrict__ rpb) {
  int i = blockIdx.x * 256 + threadIdx.x;
  const float SCALE = 0.1767766952966369f;  // 32^-0.5
  if (i < 36864) {
    int n = i / 192, k = i % 192;
    wq_t[n*192 + k] = f2b(q_w[k*192 + n] * SCALE);
  } else if (i < 110592) {
    int j = i - 36864; int n = j / 192, k = j % 192;
    wkv_t[n*192 + k] = f2b(kv_w[k*384 + n]);
  } else if (i < 147456) {
    int j = i - 110592; int n = j / 192, k = j % 192;
    wp_t[n*192 + k] = f2b(proj_w[k*192 + n]);
  } else if (i < 147648) {
    int c = i - 147456;
    qb_s[c] = q_b[c] * SCALE;
  } else if (i < 162054) {
    int j = i - 147648;
    int key = j % 49; int r = j / 49;
    int qr = r % 49; int h = r / 49;
    int di = qr/7 - key/7 + 6;
    int dj = qr%7 - key%7 + 6;
    rpb[j] = bias_table[(di*13 + dj)*6 + h];
  }
}

// ---------------- fused window attention ----------------
__global__ __launch_bounds__(256, 2) void fused_win_attn(
    const float* __restrict__ x, const float* __restrict__ mask,
    const float* __restrict__ kv_b, const float* __restrict__ proj_b,
    const unsigned short* __restrict__ wq_t, const unsigned short* __restrict__ wkv_t,
    const unsigned short* __restrict__ wp_t, const float* __restrict__ qb_s,
    const float* __restrict__ rpb, float* __restrict__ out, int nW)
{
  // swizzled LDS tiles: byte ^= ((row&7)<<4) (ohd: (row&3)<<4)
  __shared__ __align__(16) unsigned short qld[QN*192];    // 20352 B  [qrow][n]
  __shared__ __align__(16) unsigned short kld[NTOK*192];  // 18816 B  [key][n]
  __shared__ __align__(16) unsigned short vtd[192*64];    // 24576 B  [d][key] (V transposed)
  __shared__ __align__(16) unsigned short pld[QN*64];     //  6784 B  [qrow][key]
  __shared__ __align__(16) unsigned short ohd[QN*32];     //  3392 B  [qrow][d-in-head]

  const int tid = (int)threadIdx.x;
  const int w    = tid >> 6;      // wave 0..3
  const int lane = tid & 63;
  const int g    = lane >> 4;     // k-group 0..3
  const int l16  = lane & 15;
  const int b    = (int)blockIdx.x;
  const int wdx  = b % nW;
  const float* xw = x + (size_t)b * (QN*DIM);
  char* qldc = (char*)qld;
  char* kldc = (char*)kld;
  char* vtc  = (char*)vtd;
  char* pldc = (char*)pld;
  char* ohc  = (char*)ohd;
  const f32x4 fz = {0.f, 0.f, 0.f, 0.f};

  // ---- zero V pad keys 49..63 (uninit LDS may be NaN; must be exact 0 for PV) ----
  // vtd rows owned by waves 2,3 in phase 2 -> same waves zero the pad (no cross-wave race:
  // pad cols 49..63 disjoint from real cols 0..48)
  if (w >= 2) {
    int base_r = (w - 2) * 96;
    for (int it = lane; it < 96*15; it += 64) {
      int r  = base_r + it / 15;
      int ck = 49 + it % 15;
      *(unsigned short*)(vtc + r*128 + ((ck*2) ^ ((r&7)<<4))) = 0;
    }
  }

  short8 a[4][6];

  // ---- A-fragments of x for Q (token rows 0..63, clamped to 52) ----
  #pragma unroll
  for (int rt = 0; rt < 4; ++rt) {
    int row = rt*16 + l16; if (row > QN-1) row = QN-1;
    const float* p = xw + row*DIM + g*8;
    #pragma unroll
    for (int ks = 0; ks < 6; ++ks) {
      float4 u0 = *(const float4*)(p + ks*32);
      float4 u1 = *(const float4*)(p + ks*32 + 4);
      short8 t;
      t[0]=(short)f2b(u0.x); t[1]=(short)f2b(u0.y); t[2]=(short)f2b(u0.z); t[3]=(short)f2b(u0.w);
      t[4]=(short)f2b(u1.x); t[5]=(short)f2b(u1.y); t[6]=(short)f2b(u1.z); t[7]=(short)f2b(u1.w);
      a[rt][ks] = t;
    }
  }

  // ---- Phase 1: Q projection (col-split: wave w owns col-tiles 3w..3w+2) ----
  #pragma unroll
  for (int c = 0; c < 3; ++c) {
    const int n = (w*3 + c)*16 + l16;          // 0..191
    const unsigned short* wp = wq_t + n*192 + g*8;
    short8 bw[6];
    #pragma unroll
    for (int ks = 0; ks < 6; ++ks) bw[ks] = *(const short8*)(wp + ks*32);
    f32x4 acc[4] = {fz, fz, fz, fz};
    #pragma unroll
    for (int ks = 0; ks < 6; ++ks)
      #pragma unroll
      for (int rt = 0; rt < 4; ++rt)
        acc[rt] = __builtin_amdgcn_mfma_f32_16x16x32_bf16(a[rt][ks], bw[ks], acc[rt], 0, 0, 0);
    float bias = qb_s[n];
    #pragma unroll
    for (int rt = 0; rt < 4; ++rt)
      #pragma unroll
      for (int j = 0; j < 4; ++j) {
        int row = rt*16 + g*4 + j;
        if (row < QN)
          *(unsigned short*)(qldc + row*384 + ((n*2) ^ ((row&7)<<4))) = f2b(acc[rt][j] + bias);
      }
  }

  // ---- A-fragments of x for KV (token rows 4..67, clamped to 52) ----
  #pragma unroll
  for (int rt = 0; rt < 4; ++rt) {
    int row = rt*16 + l16 + NP; if (row > QN-1) row = QN-1;
    const float* p = xw + row*DIM + g*8;
    #pragma unroll
    for (int ks = 0; ks < 6; ++ks) {
      float4 u0 = *(const float4*)(p + ks*32);
      float4 u1 = *(const float4*)(p + ks*32 + 4);
      short8 t;
      t[0]=(short)f2b(u0.x); t[1]=(short)f2b(u0.y); t[2]=(short)f2b(u0.z); t[3]=(short)f2b(u0.w);
      t[4]=(short)f2b(u1.x); t[5]=(short)f2b(u1.y); t[6]=(short)f2b(u1.z); t[7]=(short)f2b(u1.w);
      a[rt][ks] = t;
    }
  }

  // ---- Phase 2: KV projection (wave w owns col-tiles 6w..6w+5 of 24) ----
  #pragma unroll
  for (int c = 0; c < 6; ++c) {
    const int ct = w*6 + c;
    const int n = ct*16 + l16;                 // 0..383
    const unsigned short* wp2 = wkv_t + n*192 + g*8;
    short8 bw[6];
    #pragma unroll
    for (int ks = 0; ks < 6; ++ks) bw[ks] = *(const short8*)(wp2 + ks*32);
    f32x4 acc[4] = {fz, fz, fz, fz};
    #pragma unroll
    for (int ks = 0; ks < 6; ++ks)
      #pragma unroll
      for (int rt = 0; rt < 4; ++rt)
        acc[rt] = __builtin_amdgcn_mfma_f32_16x16x32_bf16(a[rt][ks], bw[ks], acc[rt], 0, 0, 0);
    float bias = kv_b[n];
    if (ct < 12) {  // K part (waves 0,1): kld[key][n]
      #pragma unroll
      for (int rt = 0; rt < 4; ++rt)
        #pragma unroll
        for (int j = 0; j < 4; ++j) {
          int row = rt*16 + g*4 + j;
          if (row < NTOK)
            *(unsigned short*)(kldc + row*384 + ((n*2) ^ ((row&7)<<4))) = f2b(acc[rt][j] + bias);
        }
    } else {        // V part (waves 2,3): vtd[d][key], swizzled
      int dg = n - 192;                        // 0..191
      char* vbase = vtc + dg*128;
      int swz = (dg&7)<<4;
      #pragma unroll
      for (int rt = 0; rt < 4; ++rt)
        #pragma unroll
        for (int j = 0; j < 4; ++j) {
          int tok = rt*16 + g*4 + j;
          if (tok < NTOK)
            *(unsigned short*)(vbase + ((tok*2) ^ swz)) = f2b(acc[rt][j] + bias);
        }
    }
  }
  __syncthreads();

  // ---- Phase 3: per-head attention + fused proj partials ----
  f32x4 pacc[3][4] = { {fz,fz,fz,fz}, {fz,fz,fz,fz}, {fz,fz,fz,fz} };
  int qrow_r = w*16 + l16; if (qrow_r > QN-1) qrow_r = QN-1;  // A-frag row (this wave's tile)
  const float* maskw = mask + (size_t)wdx * 2401;

  for (int h = 0; h < 6; ++h) {
    // QK^T : wave w owns q-row-tile w; 4 key tiles
    short8 qa = *(const short8*)(qldc + qrow_r*384 + (((h*32 + g*8)*2) ^ ((qrow_r&7)<<4)));
    f32x4 s[4];
    #pragma unroll
    for (int kt = 0; kt < 4; ++kt) {
      int krow = kt*16 + l16; if (krow > NTOK-1) krow = NTOK-1;
      short8 kb = *(const short8*)(kldc + krow*384 + (((h*32 + g*8)*2) ^ ((krow&7)<<4)));
      s[kt] = __builtin_amdgcn_mfma_f32_16x16x32_bf16(qa, kb, fz, 0, 0, 0);
    }
    // rel-pos-bias + mask + key-pad fixup
    const float* rpbh = rpb + h*2401;
    float vals[4][4];
    #pragma unroll
    for (int kt = 0; kt < 4; ++kt) {
      int key = kt*16 + l16;
      #pragma unroll
      for (int j = 0; j < 4; ++j) {
        int qr = w*16 + g*4 + j;
        float sv = s[kt][j];
        if (key >= NTOK) sv = -1e30f;
        else if (qr >= NP && qr < QN) {
          int o = (qr-NP)*49 + key;
          sv += rpbh[o] + maskw[o];
        }
        vals[kt][j] = sv;
      }
    }
    // softmax per q-row (row lives on 16 lanes x 4 regs); store P (bf16) to pld
    #pragma unroll
    for (int j = 0; j < 4; ++j) {
      float m = fmaxf(fmaxf(vals[0][j], vals[1][j]), fmaxf(vals[2][j], vals[3][j]));
      m = fmaxf(m, __shfl_xor(m, 1)); m = fmaxf(m, __shfl_xor(m, 2));
      m = fmaxf(m, __shfl_xor(m, 4)); m = fmaxf(m, __shfl_xor(m, 8));
      float e0 = __expf(vals[0][j] - m), e1 = __expf(vals[1][j] - m);
      float e2 = __expf(vals[2][j] - m), e3 = __expf(vals[3][j] - m);
      float sum = e0 + e1 + e2 + e3;
      sum += __shfl_xor(sum, 1); sum += __shfl_xor(sum, 2);
      sum += __shfl_xor(sum, 4); sum += __shfl_xor(sum, 8);
      float rinv = 1.0f / sum;
      int prow = w*16 + g*4 + j;
      if (prow < QN) {
        int swz = (prow&7)<<4;
        char* pb = pldc + prow*128;
        *(unsigned short*)(pb + (((0*16+l16)*2) ^ swz)) = f2b(e0*rinv);
        *(unsigned short*)(pb + (((1*16+l16)*2) ^ swz)) = f2b(e1*rinv);
        *(unsigned short*)(pb + (((2*16+l16)*2) ^ swz)) = f2b(e2*rinv);
        *(unsigned short*)(pb + (((3*16+l16)*2) ^ swz)) = f2b(e3*rinv);
      }
    }
    // PV : o_h[qrow][dt*16+l16]; pa hoisted (ks-dependent only), vb one ds_read_b128 each
    {
      int pswz = (qrow_r&7)<<4;
      short8 pa0 = *(const short8*)(pldc + qrow_r*128 + ((16*g)      ^ pswz));
      short8 pa1 = *(const short8*)(pldc + qrow_r*128 + ((64 + 16*g) ^ pswz));
      #pragma unroll
      for (int dt = 0; dt < 2; ++dt) {
        int vrow = h*32 + dt*16 + l16;
        int vswz = (vrow&7)<<4;
        short8 vb0 = *(const short8*)(vtc + vrow*128 + ((16*g)      ^ vswz));
        short8 vb1 = *(const short8*)(vtc + vrow*128 + ((64 + 16*g) ^ vswz));
        f32x4 oacc = __builtin_amdgcn_mfma_f32_16x16x32_bf16(pa0, vb0, fz, 0, 0, 0);
        oacc = __builtin_amdgcn_mfma_f32_16x16x32_bf16(pa1, vb1, oacc, 0, 0, 0);
        #pragma unroll
        for (int j = 0; j < 4; ++j) {
          int row = w*16 + g*4 + j;
          if (row < QN)
            *(unsigned short*)(ohc + row*64 + (((dt*16 + l16)*2) ^ ((row&3)<<4))) = f2b(oacc[j]);
        }
      }
    }
    __syncthreads();
    // proj partial: K=32 slice of o @ proj_w, accumulated over heads in registers
    short8 oa[4];
    #pragma unroll
    for (int rt = 0; rt < 4; ++rt) {
      int row = rt*16 + l16; if (row > QN-1) row = QN-1;
      oa[rt] = *(const short8*)(ohc + row*64 + (((g*8)*2) ^ ((row&3)<<4)));
    }
    #pragma unroll
    for (int c = 0; c < 3; ++c) {
      int n = (w*3 + c)*16 + l16;
      short8 bw = *(const short8*)(wp_t + n*192 + h*32 + g*8);
      #pragma unroll
      for (int rt = 0; rt < 4; ++rt)
        pacc[c][rt] = __builtin_amdgcn_mfma_f32_16x16x32_bf16(oa[rt], bw, pacc[c][rt], 0, 0, 0);
    }
    __syncthreads();
  }

  // ---- epilogue: out = pacc + proj_b (fp32) ----
  float* ow = out + (size_t)b * (QN*DIM);
  #pragma unroll
  for (int c = 0; c < 3; ++c) {
    int n = (w*3 + c)*16 + l16;
    float bias = proj_b[n];
    #pragma unroll
    for (int rt = 0; rt < 4; ++rt)
      #pragma unroll
      for (int j = 0; j < 4; ++j) {
        int row = rt*16 + g*4 + j;
        if (row < QN) ow[row*192 + n] = pacc[c][rt][j] + bias;
      }
  }
}

extern "C" void kernel_launch(void* const* d_in, const int* in_sizes, int n_in,
                              void* d_out, int out_size, void* d_ws, size_t ws_size,
                              hipStream_t stream) {
  const float* x          = (const float*)d_in[0];
  const float* mask       = (const float*)d_in[1];
  const float* q_w        = (const float*)d_in[2];
  const float* q_b        = (const float*)d_in[3];
  const float* kv_w       = (const float*)d_in[4];
  const float* kv_b       = (const float*)d_in[5];
  const float* proj_w     = (const float*)d_in[6];
  const float* proj_b     = (const float*)d_in[7];
  const float* bias_table = (const float*)d_in[8];

  const int B  = in_sizes[0] / (QN*DIM);   // 4096
  const int nW = in_sizes[1] / (49*49);    // 64

  // workspace layout (bytes, all 16-aligned)
  char* ws = (char*)d_ws;
  unsigned short* wq_t  = (unsigned short*)(ws + 0);        // 73728 B
  unsigned short* wkv_t = (unsigned short*)(ws + 73728);    // 147456 B
  unsigned short* wp_t  = (unsigned short*)(ws + 221184);   // 73728 B
  float*          qb_s  = (float*)(ws + 294912);            // 768 B
  float*          rpb   = (float*)(ws + 295680);            // 6*49*49*4 = 57624 B
  size_t need = 295680 + 57624;
  if (ws_size < need) return;  // loud failure (validation will flag)

  prep_all<<<634, 256, 0, stream>>>(q_w, q_b, kv_w, proj_w, bias_table,
                                    wq_t, wkv_t, wp_t, qb_s, rpb);
  fused_win_attn<<<B, 256, 0, stream>>>(x, mask, kv_b, proj_b, wq_t, wkv_t, wp_t, qb_s,
                                        rpb, (float*)d_out, nW);
}

// Round 3
// 712.782 us; speedup vs baseline: 1.0112x; 1.0112x over previous
//
#include <hip/hip_runtime.h>
#include <hip/hip_bf16.h>

#define QN 53
#define NTOK 49
#define DIM 192
#define NP 4

typedef __attribute__((ext_vector_type(8))) short short8;
typedef __attribute__((ext_vector_type(4))) float f32x4;

__device__ __forceinline__ unsigned short f2b(float f) {
  union { __hip_bfloat16 h; unsigned short u; } cv;
  cv.h = __float2bfloat16(f);
  return cv.u;
}
__device__ __forceinline__ float b2f(unsigned short u) {
  union { unsigned int i; float f; } cv; cv.i = ((unsigned int)u) << 16; return cv.f;
}

// ---------------- prep: bf16 transposed weights (+scale fold) + rpb + comb ----------------
// rpb: [h][qr][key] f32 (6*2401); comb: [wdx][h][qr][key] bf16 (nW*6*2401), = rpb + mask
__global__ void prep_all(const float* __restrict__ q_w, const float* __restrict__ q_b,
                         const float* __restrict__ kv_w, const float* __restrict__ proj_w,
                         const float* __restrict__ bias_table, const float* __restrict__ mask,
                         unsigned short* __restrict__ wq_t, unsigned short* __restrict__ wkv_t,
                         unsigned short* __restrict__ wp_t, float* __restrict__ qb_s,
                         float* __restrict__ rpb, unsigned short* __restrict__ comb, int combN) {
  int i = blockIdx.x * 256 + threadIdx.x;
  const float SCALE = 0.1767766952966369f;  // 32^-0.5
  if (i < 36864) {
    int n = i / 192, k = i % 192;
    wq_t[n*192 + k] = f2b(q_w[k*192 + n] * SCALE);
  } else if (i < 110592) {
    int j = i - 36864; int n = j / 192, k = j % 192;
    wkv_t[n*192 + k] = f2b(kv_w[k*384 + n]);
  } else if (i < 147456) {
    int j = i - 110592; int n = j / 192, k = j % 192;
    wp_t[n*192 + k] = f2b(proj_w[k*192 + n]);
  } else if (i < 147648) {
    int c = i - 147456;
    qb_s[c] = q_b[c] * SCALE;
  } else if (i < 162054) {
    int j = i - 147648;
    int key = j % 49; int r = j / 49;
    int qr = r % 49; int h = r / 49;
    int di = qr/7 - key/7 + 6;
    int dj = qr%7 - key%7 + 6;
    rpb[j] = bias_table[(di*13 + dj)*6 + h];
  } else if (i - 162054 < combN) {
    int j = i - 162054;
    int key = j % 49; int r = j / 49;
    int qr = r % 49; r /= 49;
    int h = r % 6; int wdx = r / 6;
    int di = qr/7 - key/7 + 6;
    int dj = qr%7 - key%7 + 6;
    comb[j] = f2b(bias_table[(di*13 + dj)*6 + h] + mask[(wdx*49 + qr)*49 + key]);
  }
}

// ---------------- fused window attention ----------------
__global__ __launch_bounds__(256, 2) void fused_win_attn(
    const float* __restrict__ x, const float* __restrict__ mask,
    const float* __restrict__ kv_b, const float* __restrict__ proj_b,
    const unsigned short* __restrict__ wq_t, const unsigned short* __restrict__ wkv_t,
    const unsigned short* __restrict__ wp_t, const float* __restrict__ qb_s,
    const float* __restrict__ rpb, const unsigned short* __restrict__ comb,
    float* __restrict__ out, int nW, int have_comb)
{
  // swizzled LDS tiles: byte ^= ((row&7)<<4)
  __shared__ __align__(16) unsigned short qld[QN*192];    // 20352 B  [qrow][n]; later O[qrow][n]
  __shared__ __align__(16) unsigned short kld[NTOK*192];  // 18816 B  [key][n]
  __shared__ __align__(16) unsigned short vtd[192*64];    // 24576 B  [d][key] (V transposed)
  __shared__ __align__(16) unsigned short pld[QN*64];     //  6784 B  [qrow][key]

  const int tid = (int)threadIdx.x;
  const int w    = tid >> 6;      // wave 0..3
  const int lane = tid & 63;
  const int g    = lane >> 4;     // k-group 0..3
  const int l16  = lane & 15;
  const int b    = (int)blockIdx.x;
  const int wdx  = b % nW;
  const float* xw = x + (size_t)b * (QN*DIM);
  char* qldc = (char*)qld;
  char* kldc = (char*)kld;
  char* vtc  = (char*)vtd;
  char* pldc = (char*)pld;
  const f32x4 fz = {0.f, 0.f, 0.f, 0.f};

  // ---- zero V pad keys 49..63 (uninit LDS may be NaN; must be exact 0 for PV) ----
  if (w >= 2) {
    int base_r = (w - 2) * 96;
    for (int it = lane; it < 96*15; it += 64) {
      int r  = base_r + it / 15;
      int ck = 49 + it % 15;
      *(unsigned short*)(vtc + r*128 + ((ck*2) ^ ((r&7)<<4))) = 0;
    }
  }

  short8 a[4][6];

  // ---- A-fragments of x for Q (token rows 0..63, clamped to 52) ----
  #pragma unroll
  for (int rt = 0; rt < 4; ++rt) {
    int row = rt*16 + l16; if (row > QN-1) row = QN-1;
    const float* p = xw + row*DIM + g*8;
    #pragma unroll
    for (int ks = 0; ks < 6; ++ks) {
      float4 u0 = *(const float4*)(p + ks*32);
      float4 u1 = *(const float4*)(p + ks*32 + 4);
      short8 t;
      t[0]=(short)f2b(u0.x); t[1]=(short)f2b(u0.y); t[2]=(short)f2b(u0.z); t[3]=(short)f2b(u0.w);
      t[4]=(short)f2b(u1.x); t[5]=(short)f2b(u1.y); t[6]=(short)f2b(u1.z); t[7]=(short)f2b(u1.w);
      a[rt][ks] = t;
    }
  }

  // ---- Phase 1: Q projection (wave w owns col-tiles 3w..3w+2); bias in acc init ----
  #pragma unroll
  for (int c = 0; c < 3; ++c) {
    const int n = (w*3 + c)*16 + l16;          // 0..191
    const unsigned short* wp = wq_t + n*192 + g*8;
    short8 bw[6];
    #pragma unroll
    for (int ks = 0; ks < 6; ++ks) bw[ks] = *(const short8*)(wp + ks*32);
    float bias = qb_s[n];
    f32x4 acc[4] = { {bias,bias,bias,bias}, {bias,bias,bias,bias},
                     {bias,bias,bias,bias}, {bias,bias,bias,bias} };
    #pragma unroll
    for (int ks = 0; ks < 6; ++ks)
      #pragma unroll
      for (int rt = 0; rt < 4; ++rt)
        acc[rt] = __builtin_amdgcn_mfma_f32_16x16x32_bf16(a[rt][ks], bw[ks], acc[rt], 0, 0, 0);
    #pragma unroll
    for (int rt = 0; rt < 4; ++rt)
      #pragma unroll
      for (int j = 0; j < 4; ++j) {
        int row = rt*16 + g*4 + j;
        if (row < QN)
          *(unsigned short*)(qldc + row*384 + ((n*2) ^ ((row&7)<<4))) = f2b(acc[rt][j]);
      }
  }

  // ---- A-fragments of x for KV (token rows 4..67, clamped to 52) ----
  #pragma unroll
  for (int rt = 0; rt < 4; ++rt) {
    int row = rt*16 + l16 + NP; if (row > QN-1) row = QN-1;
    const float* p = xw + row*DIM + g*8;
    #pragma unroll
    for (int ks = 0; ks < 6; ++ks) {
      float4 u0 = *(const float4*)(p + ks*32);
      float4 u1 = *(const float4*)(p + ks*32 + 4);
      short8 t;
      t[0]=(short)f2b(u0.x); t[1]=(short)f2b(u0.y); t[2]=(short)f2b(u0.z); t[3]=(short)f2b(u0.w);
      t[4]=(short)f2b(u1.x); t[5]=(short)f2b(u1.y); t[6]=(short)f2b(u1.z); t[7]=(short)f2b(u1.w);
      a[rt][ks] = t;
    }
  }

  // ---- Phase 2: KV projection (wave w owns col-tiles 6w..6w+5 of 24) ----
  #pragma unroll
  for (int c = 0; c < 6; ++c) {
    const int ct = w*6 + c;
    const int n = ct*16 + l16;                 // 0..383
    const unsigned short* wp2 = wkv_t + n*192 + g*8;
    short8 bw[6];
    #pragma unroll
    for (int ks = 0; ks < 6; ++ks) bw[ks] = *(const short8*)(wp2 + ks*32);
    float bias = kv_b[n];
    f32x4 acc[4] = { {bias,bias,bias,bias}, {bias,bias,bias,bias},
                     {bias,bias,bias,bias}, {bias,bias,bias,bias} };
    #pragma unroll
    for (int ks = 0; ks < 6; ++ks)
      #pragma unroll
      for (int rt = 0; rt < 4; ++rt)
        acc[rt] = __builtin_amdgcn_mfma_f32_16x16x32_bf16(a[rt][ks], bw[ks], acc[rt], 0, 0, 0);
    if (ct < 12) {  // K part (waves 0,1): kld[key][n]
      #pragma unroll
      for (int rt = 0; rt < 4; ++rt)
        #pragma unroll
        for (int j = 0; j < 4; ++j) {
          int row = rt*16 + g*4 + j;
          if (row < NTOK)
            *(unsigned short*)(kldc + row*384 + ((n*2) ^ ((row&7)<<4))) = f2b(acc[rt][j]);
        }
    } else {        // V part (waves 2,3): vtd[d][key], swizzled
      int dg = n - 192;                        // 0..191
      char* vbase = vtc + dg*128;
      int swz = (dg&7)<<4;
      #pragma unroll
      for (int rt = 0; rt < 4; ++rt)
        #pragma unroll
        for (int j = 0; j < 4; ++j) {
          int tok = rt*16 + g*4 + j;
          if (tok < NTOK)
            *(unsigned short*)(vbase + ((tok*2) ^ swz)) = f2b(acc[rt][j]);
        }
    }
  }
  __syncthreads();   // (barrier #1: Q/K/V visible to all waves)

  // ---- Phase 3: per-head attention, O accumulated in registers, NO barriers ----
  f32x4 oacc[12];
  #pragma unroll
  for (int t = 0; t < 12; ++t) oacc[t] = fz;

  int qrow_r = w*16 + l16; if (qrow_r > QN-1) qrow_r = QN-1;  // own-tile A-frag row
  const int pswz = (qrow_r&7)<<4;
  const unsigned short* combw = comb + (size_t)wdx * (6*2401);
  const float* maskw = mask + (size_t)wdx * 2401;

  #pragma unroll
  for (int h = 0; h < 6; ++h) {
    // QK^T : wave w owns q-row-tile w; 4 key tiles
    short8 qa = *(const short8*)(qldc + qrow_r*384 + (((h*32 + g*8)*2) ^ pswz));
    f32x4 s[4];
    #pragma unroll
    for (int kt = 0; kt < 4; ++kt) {
      int krow = kt*16 + l16; if (krow > NTOK-1) krow = NTOK-1;
      short8 kb = *(const short8*)(kldc + krow*384 + (((h*32 + g*8)*2) ^ ((krow&7)<<4)));
      s[kt] = __builtin_amdgcn_mfma_f32_16x16x32_bf16(qa, kb, fz, 0, 0, 0);
    }
    // bias+mask fixup (single bf16 comb load per element when available)
    float vals[4][4];
    #pragma unroll
    for (int kt = 0; kt < 4; ++kt) {
      int key = kt*16 + l16;
      #pragma unroll
      for (int j = 0; j < 4; ++j) {
        int qr = w*16 + g*4 + j;
        float sv = s[kt][j];
        if (key >= NTOK) sv = -1e30f;
        else if (qr >= NP && qr < QN) {
          int o = (qr-NP)*49 + key;
          sv += have_comb ? b2f(combw[h*2401 + o]) : (rpb[h*2401 + o] + maskw[o]);
        }
        vals[kt][j] = sv;
      }
    }
    // softmax per q-row (row on 16 lanes x 4 regs); store P (bf16) to own pld rows
    #pragma unroll
    for (int j = 0; j < 4; ++j) {
      float m = fmaxf(fmaxf(vals[0][j], vals[1][j]), fmaxf(vals[2][j], vals[3][j]));
      m = fmaxf(m, __shfl_xor(m, 1)); m = fmaxf(m, __shfl_xor(m, 2));
      m = fmaxf(m, __shfl_xor(m, 4)); m = fmaxf(m, __shfl_xor(m, 8));
      float e0 = __expf(vals[0][j] - m), e1 = __expf(vals[1][j] - m);
      float e2 = __expf(vals[2][j] - m), e3 = __expf(vals[3][j] - m);
      float sum = e0 + e1 + e2 + e3;
      sum += __shfl_xor(sum, 1); sum += __shfl_xor(sum, 2);
      sum += __shfl_xor(sum, 4); sum += __shfl_xor(sum, 8);
      float rinv = 1.0f / sum;
      int prow = w*16 + g*4 + j;
      if (prow < QN) {
        int swz = (prow&7)<<4;
        char* pb = pldc + prow*128;
        *(unsigned short*)(pb + (((0*16+l16)*2) ^ swz)) = f2b(e0*rinv);
        *(unsigned short*)(pb + (((1*16+l16)*2) ^ swz)) = f2b(e1*rinv);
        *(unsigned short*)(pb + (((2*16+l16)*2) ^ swz)) = f2b(e2*rinv);
        *(unsigned short*)(pb + (((3*16+l16)*2) ^ swz)) = f2b(e3*rinv);
      }
    }
    // PV into register O (intra-wave pld read; in-order LDS per wave => no barrier)
    {
      short8 pa0 = *(const short8*)(pldc + qrow_r*128 + ((16*g)      ^ pswz));
      short8 pa1 = *(const short8*)(pldc + qrow_r*128 + ((64 + 16*g) ^ pswz));
      #pragma unroll
      for (int dt = 0; dt < 2; ++dt) {
        int vrow = h*32 + dt*16 + l16;
        int vswz = (vrow&7)<<4;
        short8 vb0 = *(const short8*)(vtc + vrow*128 + ((16*g)      ^ vswz));
        short8 vb1 = *(const short8*)(vtc + vrow*128 + ((64 + 16*g) ^ vswz));
        oacc[h*2+dt] = __builtin_amdgcn_mfma_f32_16x16x32_bf16(pa0, vb0, oacc[h*2+dt], 0, 0, 0);
        oacc[h*2+dt] = __builtin_amdgcn_mfma_f32_16x16x32_bf16(pa1, vb1, oacc[h*2+dt], 0, 0, 0);
      }
    }
  }

  // ---- stage O (bf16) into qld (own rows; Q dead now) ----
  #pragma unroll
  for (int t = 0; t < 12; ++t) {
    #pragma unroll
    for (int j = 0; j < 4; ++j) {
      int row = w*16 + g*4 + j;
      if (row < QN) {
        int colb = (t*16 + l16)*2;
        *(unsigned short*)(qldc + row*384 + (colb ^ ((row&7)<<4))) = f2b(oacc[t][j]);
      }
    }
  }
  __syncthreads();   // (barrier #2: O visible to all waves)

  // ---- final proj: out = O @ proj_w + proj_b (72 MFMA/wave) ----
  short8 oa[4][6];
  #pragma unroll
  for (int rt = 0; rt < 4; ++rt) {
    int row = rt*16 + l16; if (row > QN-1) row = QN-1;
    int swz = (row&7)<<4;
    #pragma unroll
    for (int ks = 0; ks < 6; ++ks)
      oa[rt][ks] = *(const short8*)(qldc + row*384 + (((ks*32 + g*8)*2) ^ swz));
  }
  float* ow = out + (size_t)b * (QN*DIM);
  #pragma unroll
  for (int c = 0; c < 3; ++c) {
    const int n = (w*3 + c)*16 + l16;
    const unsigned short* wpp = wp_t + n*192 + g*8;
    short8 bw[6];
    #pragma unroll
    for (int ks = 0; ks < 6; ++ks) bw[ks] = *(const short8*)(wpp + ks*32);
    float bias = proj_b[n];
    f32x4 acc[4] = { {bias,bias,bias,bias}, {bias,bias,bias,bias},
                     {bias,bias,bias,bias}, {bias,bias,bias,bias} };
    #pragma unroll
    for (int ks = 0; ks < 6; ++ks)
      #pragma unroll
      for (int rt = 0; rt < 4; ++rt)
        acc[rt] = __builtin_amdgcn_mfma_f32_16x16x32_bf16(oa[rt][ks], bw[ks], acc[rt], 0, 0, 0);
    #pragma unroll
    for (int rt = 0; rt < 4; ++rt)
      #pragma unroll
      for (int j = 0; j < 4; ++j) {
        int row = rt*16 + g*4 + j;
        if (row < QN) ow[row*192 + n] = acc[rt][j];
      }
  }
}

extern "C" void kernel_launch(void* const* d_in, const int* in_sizes, int n_in,
                              void* d_out, int out_size, void* d_ws, size_t ws_size,
                              hipStream_t stream) {
  const float* x          = (const float*)d_in[0];
  const float* mask       = (const float*)d_in[1];
  const float* q_w        = (const float*)d_in[2];
  const float* q_b        = (const float*)d_in[3];
  const float* kv_w       = (const float*)d_in[4];
  const float* kv_b       = (const float*)d_in[5];
  const float* proj_w     = (const float*)d_in[6];
  const float* proj_b     = (const float*)d_in[7];
  const float* bias_table = (const float*)d_in[8];

  const int B  = in_sizes[0] / (QN*DIM);   // 4096
  const int nW = in_sizes[1] / (49*49);    // 64

  // workspace layout (bytes, all 16-aligned)
  char* ws = (char*)d_ws;
  unsigned short* wq_t  = (unsigned short*)(ws + 0);        // 73728 B
  unsigned short* wkv_t = (unsigned short*)(ws + 73728);    // 147456 B
  unsigned short* wp_t  = (unsigned short*)(ws + 221184);   // 73728 B
  float*          qb_s  = (float*)(ws + 294912);            // 768 B
  float*          rpb   = (float*)(ws + 295680);            // 57624 B
  size_t comb_off = 353312;  // 16-aligned
  unsigned short* comb  = (unsigned short*)(ws + comb_off);
  const int combN = nW * 6 * 2401;
  size_t need_base = comb_off;
  size_t need_comb = comb_off + (size_t)combN * 2;
  if (ws_size < need_base) return;  // loud failure
  int have_comb = (ws_size >= need_comb) ? 1 : 0;

  int prepN = 162054 + (have_comb ? combN : 0);
  prep_all<<<(prepN + 255) / 256, 256, 0, stream>>>(
      q_w, q_b, kv_w, proj_w, bias_table, mask,
      wq_t, wkv_t, wp_t, qb_s, rpb, comb, have_comb ? combN : 0);
  fused_win_attn<<<B, 256, 0, stream>>>(x, mask, kv_b, proj_b, wq_t, wkv_t, wp_t, qb_s,
                                        rpb, comb, (float*)d_out, nW, have_comb);
}